// Round 6
// baseline (830.112 us; speedup 1.0000x reference)
//
#include <hip/hip_runtime.h>
#include <stdint.h>

#define NCLS 80
#define CELLS 8400      // 6400 + 1600 + 400
#define PRE 1000
#define KEEP 100
#define CAP 4096        // fallback candidate cap
#define NBINS 16384     // fallback histogram bins
#define NIMG 32
#define SUBS 8
#define SUBCAP 2048     // per-sub store cap (total 16384/image)
#define GBINS 4096      // gather-phase LDS histogram bins
#define COMPCAP 2048
#define T0 0.75f        // static pre-store threshold (top-1000 cutoff ~0.82 for N(0,1))
#define SCREEN 1.0886f  // logit(0.75)=1.0986 minus slack; exact test done on sigm product

__device__ __forceinline__ float sigm(float x) { return 1.0f / (1.0f + __expf(-x)); }

__device__ __forceinline__ void lvlinfo(int cell, int& li, int& loc, int& HW) {
  if (cell < 6400)      { li = 0; loc = cell;        HW = 6400; }
  else if (cell < 8000) { li = 1; loc = cell - 6400; HW = 1600; }
  else                  { li = 2; loc = cell - 8000; HW = 400;  }
}

// ---------------- K1: single full pass over cls/obj ----------------
// Thread owns 4 cells (one float4 position) and 40 channels (class half h).
// Batch of 8 float4 loads -> 32-elem max -> branch: the max consumes every value,
// forcing all 8 loads in flight before any use. va/vb double-buffer keeps loads
// of batch g+1 in flight while batch g is processed (fully unrolled; rule #20).
__global__ __launch_bounds__(256) void k_pass1(
    const float* __restrict__ cls0, const float* __restrict__ cls1, const float* __restrict__ cls2,
    const float* __restrict__ obj0, const float* __restrict__ obj1, const float* __restrict__ obj2,
    uint32_t* __restrict__ cnt75, uint64_t* __restrict__ cand75) {
  const int b = blockIdx.y;
  const int bx = blockIdx.x;
  const int sb = bx >> 1;               // 9 spatial blocks
  const int h  = bx & 1;                // class chunk: [h*40, h*40+40)
  const int c0cell = (sb * 256 + threadIdx.x) * 4;
  if (c0cell >= CELLS) return;
  int li, loc, HW; lvlinfo(c0cell, li, loc, HW);
  const float* cls = li == 0 ? cls0 : (li == 1 ? cls1 : cls2);
  const float* obj = li == 0 ? obj0 : (li == 1 ? obj1 : obj2);

  float4 o0 = *(const float4*)(obj + ((size_t)b * 3 + 0) * HW + loc);
  float4 o1 = *(const float4*)(obj + ((size_t)b * 3 + 1) * HW + loc);
  float4 o2 = *(const float4*)(obj + ((size_t)b * 3 + 2) * HW + loc);
  float os[3][4];
  os[0][0] = sigm(o0.x); os[0][1] = sigm(o0.y); os[0][2] = sigm(o0.z); os[0][3] = sigm(o0.w);
  os[1][0] = sigm(o1.x); os[1][1] = sigm(o1.y); os[1][2] = sigm(o1.z); os[1][3] = sigm(o1.w);
  os[2][0] = sigm(o2.x); os[2][1] = sigm(o2.y); os[2][2] = sigm(o2.z); os[2][3] = sigm(o2.w);

  const int sub = bx & (SUBS - 1);

#define LD(dst, GQ) { _Pragma("unroll") for (int u = 0; u < 8; ++u) \
    dst[u] = *(const float4*)(cp + (size_t)((GQ) * 8 + u) * HW); }
#define PR(src, GQ) { \
    float mx = fmaxf(fmaxf(src[0].x, src[0].y), fmaxf(src[0].z, src[0].w)); \
    _Pragma("unroll") for (int u = 1; u < 8; ++u) \
      mx = fmaxf(mx, fmaxf(fmaxf(src[u].x, src[u].y), fmaxf(src[u].z, src[u].w))); \
    if (mx > SCREEN) { \
      _Pragma("unroll") for (int u = 0; u < 8; ++u) { \
        const int c = h * 40 + (GQ) * 8 + u; \
        float vv[4] = { src[u].x, src[u].y, src[u].z, src[u].w }; \
        _Pragma("unroll") for (int k = 0; k < 4; ++k) { \
          if (vv[k] > SCREEN) { \
            float s = sigm(vv[k]) * os[p][k]; \
            if (s > T0) { \
              uint32_t slot = atomicAdd(&cnt75[b * SUBS + sub], 1u); \
              if (slot < SUBCAP) { \
                uint32_t flat = (uint32_t)(((c0cell + k) * 3 + p) * 80 + c); \
                cand75[((size_t)(b * SUBS + sub)) * SUBCAP + slot] = \
                    ((uint64_t)__float_as_uint(s) << 32) | (uint64_t)(0xFFFFFFFFu - flat); \
              } } } } } } }

#pragma unroll
  for (int p = 0; p < 3; ++p) {
    const float* cp = cls + ((size_t)b * 240 + p * 80 + h * 40) * HW + loc;
    float4 va[8], vb[8];
    LD(va, 0)
    LD(vb, 1) PR(va, 0)
    LD(va, 2) PR(vb, 1)
    LD(vb, 3) PR(va, 2)
    LD(va, 4) PR(vb, 3)
    PR(va, 4)
  }
#undef LD
#undef PR
}

// ---------------- K3: per-image gather + exact top-1000 + decode; sets per-image fb flag ----
__global__ __launch_bounds__(1024) void k_gather(
    const uint64_t* __restrict__ cand75, const uint32_t* __restrict__ cnt75,
    uint32_t* __restrict__ flags,
    const float* __restrict__ bbox0, const float* __restrict__ bbox1, const float* __restrict__ bbox2,
    const float* __restrict__ priors, const float* __restrict__ strides,
    float* __restrict__ topS, int* __restrict__ topLab, float* __restrict__ topBox,
    uint32_t* __restrict__ nvArr) {
  __shared__ uint32_t hist[GBINS];
  __shared__ uint64_t comp[COMPCAP];
  __shared__ uint32_t seg[64];
  __shared__ uint32_t ncomp_s, cb_s;
  const int b = blockIdx.x;
  const int tid = threadIdx.x;
  uint32_t tot = 0; bool bad = false;
  for (int s = 0; s < SUBS; ++s) {
    uint32_t cc = cnt75[b * SUBS + s];
    tot += cc;
    if (cc > SUBCAP) bad = true;
  }
  if (tot < (uint32_t)PRE) bad = true;
  if (bad) { if (tid == 0) flags[b] = 1u; return; }

  for (int i = tid; i < GBINS; i += 1024) hist[i] = 0;
  if (tid == 0) ncomp_s = 0;
  __syncthreads();
  for (int s = 0; s < SUBS; ++s) {
    uint32_t c = cnt75[b * SUBS + s];
    const uint64_t* src = cand75 + ((size_t)(b * SUBS + s)) * SUBCAP;
    for (int i = tid; i < (int)c; i += 1024) {
      uint32_t hi = (uint32_t)(src[i] >> 32);
      uint32_t bin = (hi - 0x3F400000u) >> 10;
      if (bin > GBINS - 1) bin = GBINS - 1;
      atomicAdd(&hist[bin], 1u);
    }
  }
  __syncthreads();
  if (tid < 64) {
    uint32_t s = 0;
    for (int k = 0; k < 64; ++k) s += hist[tid * 64 + k];
    seg[tid] = s;
  }
  __syncthreads();
  if (tid == 0) {
    uint32_t acc = 0; int segi = 0;
    for (int i = 63; i >= 0; --i) {
      if (acc + seg[i] >= (uint32_t)PRE) { segi = i; break; }
      acc += seg[i];
    }
    uint32_t cb = 0;
    for (int k = 63; k >= 0; --k) {
      acc += hist[segi * 64 + k];
      if (acc >= (uint32_t)PRE) { cb = (uint32_t)(segi * 64 + k); break; }
    }
    cb_s = cb;
  }
  __syncthreads();
  const uint32_t cb = cb_s;
  for (int s = 0; s < SUBS; ++s) {
    uint32_t c = cnt75[b * SUBS + s];
    const uint64_t* src = cand75 + ((size_t)(b * SUBS + s)) * SUBCAP;
    for (int i = tid; i < (int)c; i += 1024) {
      uint64_t key = src[i];
      uint32_t hi = (uint32_t)(key >> 32);
      uint32_t bin = (hi - 0x3F400000u) >> 10;
      if (bin > GBINS - 1) bin = GBINS - 1;
      if (bin >= cb) {
        uint32_t pos = atomicAdd(&ncomp_s, 1u);
        if (pos < COMPCAP) comp[pos] = key;
      }
    }
  }
  __syncthreads();
  const uint32_t ncomp = ncomp_s;
  if (ncomp > COMPCAP) { if (tid == 0) flags[b] = 1u; return; }
  const int N = (ncomp <= 1024u) ? 1024 : COMPCAP;   // adaptive sort size
  for (int i = tid; i < N; i += 1024) if (i >= (int)ncomp) comp[i] = 0ull;
  __syncthreads();
  for (int k = 2; k <= N; k <<= 1) {
    for (int j = k >> 1; j > 0; j >>= 1) {
      for (int i = tid; i < N; i += 1024) {
        int p = i ^ j;
        if (p > i) {
          uint64_t a = comp[i], c = comp[p];
          bool asc = (i & k) != 0;
          if (asc ? (a > c) : (a < c)) { comp[i] = c; comp[p] = a; }
        }
      }
      __syncthreads();
    }
  }
  if (tid == 0) nvArr[b] = (uint32_t)PRE;
  for (int t = tid; t < PRE; t += 1024) {
    uint64_t key = comp[t];
    float sc = __uint_as_float((uint32_t)(key >> 32));
    uint32_t flat = 0xFFFFFFFFu - (uint32_t)(key & 0xFFFFFFFFull);
    uint32_t n = flat / 80u; int lab = (int)(flat - n * 80u);
    uint32_t g = n / 3u; uint32_t p = n - g * 3u;
    int li, loc, HW; lvlinfo((int)g, li, loc, HW);
    const float* bb = li == 0 ? bbox0 : (li == 1 ? bbox1 : bbox2);
    size_t o = ((size_t)b * 12 + p * 4) * HW + loc;
    float p0 = sigm(bb[o]);
    float p1 = sigm(bb[o + (size_t)HW]);
    float p2 = sigm(bb[o + 2 * (size_t)HW]);
    float p3 = sigm(bb[o + 3 * (size_t)HW]);
    float4 pr = *(const float4*)(priors + (size_t)n * 4);
    float st = strides[n];
    float cx = (pr.x + pr.z) * 0.5f, cy = (pr.y + pr.w) * 0.5f;
    float w = pr.z - pr.x, hh = pr.w - pr.y;
    float xc = (p0 - 0.5f) * 2.0f * st + cx;
    float yc = (p1 - 0.5f) * 2.0f * st + cy;
    float wp = p2 * 2.0f; wp = wp * wp * w;
    float hp = p3 * 2.0f; hp = hp * hp * hh;
    topS[(size_t)b * PRE + t] = sc;
    topLab[(size_t)b * PRE + t] = lab;
    *(float4*)(topBox + ((size_t)b * PRE + t) * 4) =
        make_float4(xc - wp * 0.5f, yc - hp * 0.5f, xc + wp * 0.5f, yc + hp * 0.5f);
  }
}

// ---------------- gated zero of fallback histogram (runs only if any flag set) ----------
__global__ __launch_bounds__(256) void k_zero_hist(uint32_t* __restrict__ hist,
                                                   const uint32_t* __restrict__ flags) {
  __shared__ uint32_t any;
  if (threadIdx.x == 0) {
    uint32_t a = 0;
    for (int i = 0; i < NIMG; ++i) a |= flags[i];
    any = a;
  }
  __syncthreads();
  if (!any) return;
  const int total = NIMG * NBINS;
  for (int i = blockIdx.x * 256 + threadIdx.x; i < total; i += gridDim.x * 256)
    hist[i] = 0;
}

// ================= FALLBACK PATH (per-image flag; never runs for typical data) ============
__global__ __launch_bounds__(256) void k_hist_fb(
    const float* __restrict__ cls0, const float* __restrict__ cls1, const float* __restrict__ cls2,
    const float* __restrict__ obj0, const float* __restrict__ obj1, const float* __restrict__ obj2,
    uint32_t* __restrict__ hist, const uint32_t* __restrict__ flags) {
  const int b = blockIdx.y;
  if (flags[b] == 0u) return;
  __shared__ uint32_t h[NBINS];
  for (int i = threadIdx.x; i < NBINS; i += 256) h[i] = 0;
  __syncthreads();
  const int c0 = (blockIdx.x * 256 + threadIdx.x) * 4;
  if (c0 < CELLS) {
    int li, loc, HW; lvlinfo(c0, li, loc, HW);
    const float* cls = li == 0 ? cls0 : (li == 1 ? cls1 : cls2);
    const float* obj = li == 0 ? obj0 : (li == 1 ? obj1 : obj2);
    float os[3][4];
#pragma unroll
    for (int p = 0; p < 3; ++p) {
      float4 o = *(const float4*)(obj + ((size_t)b * 3 + p) * HW + loc);
      os[p][0] = sigm(o.x); os[p][1] = sigm(o.y); os[p][2] = sigm(o.z); os[p][3] = sigm(o.w);
    }
    for (int p = 0; p < 3; ++p) {
      const float* cp = cls + ((size_t)b * 240 + p * 80) * HW + loc;
      for (int c = 0; c < 80; ++c) {
        float4 v = *(const float4*)(cp + (size_t)c * HW);
        float sv[4] = { sigm(v.x) * os[p][0], sigm(v.y) * os[p][1],
                        sigm(v.z) * os[p][2], sigm(v.w) * os[p][3] };
#pragma unroll
        for (int k = 0; k < 4; ++k) {
          if (sv[k] > 0.25f) {
            uint32_t key = (__float_as_uint(sv[k]) - 0x3E800000u) >> 10;
            if (key > NBINS - 1) key = NBINS - 1;
            atomicAdd(&h[key], 1u);
          }
        }
      }
    }
  }
  __syncthreads();
  for (int i = threadIdx.x; i < NBINS; i += 256) {
    uint32_t v = h[i];
    if (v) atomicAdd(&hist[(size_t)b * NBINS + i], v);
  }
}

__global__ __launch_bounds__(256) void k_cutoff_fb(const uint32_t* __restrict__ hist,
                                                   uint32_t* __restrict__ cutoff,
                                                   const uint32_t* __restrict__ flags) {
  const int b = blockIdx.x;
  if (flags[b] == 0u) return;
  __shared__ uint32_t seg[256];
  const uint32_t* hb = hist + (size_t)b * NBINS;
  uint32_t s = 0;
  for (int k = 0; k < 64; ++k) s += hb[threadIdx.x * 64 + k];
  seg[threadIdx.x] = s;
  __syncthreads();
  if (threadIdx.x == 0) {
    uint32_t acc = 0; int segi = -1;
    for (int i = 255; i >= 0; --i) {
      if (acc + seg[i] >= (uint32_t)PRE) { segi = i; break; }
      acc += seg[i];
    }
    uint32_t cut = 0;
    if (segi >= 0) {
      for (int k = 63; k >= 0; --k) {
        acc += hb[segi * 64 + k];
        if (acc >= (uint32_t)PRE) { cut = (uint32_t)(segi * 64 + k); break; }
      }
    }
    cutoff[b] = cut;
  }
}

__global__ __launch_bounds__(256) void k_collect_fb(
    const float* __restrict__ cls0, const float* __restrict__ cls1, const float* __restrict__ cls2,
    const float* __restrict__ obj0, const float* __restrict__ obj1, const float* __restrict__ obj2,
    const uint32_t* __restrict__ cutoff, uint32_t* __restrict__ candCount,
    uint64_t* __restrict__ cand, const uint32_t* __restrict__ flags) {
  const int b = blockIdx.y;
  if (flags[b] == 0u) return;
  const int c0 = (blockIdx.x * 256 + threadIdx.x) * 4;
  if (c0 >= CELLS) return;
  const uint32_t cut = cutoff[b];
  int li, loc, HW; lvlinfo(c0, li, loc, HW);
  const float* cls = li == 0 ? cls0 : (li == 1 ? cls1 : cls2);
  const float* obj = li == 0 ? obj0 : (li == 1 ? obj1 : obj2);
  float os[3][4];
#pragma unroll
  for (int p = 0; p < 3; ++p) {
    float4 o = *(const float4*)(obj + ((size_t)b * 3 + p) * HW + loc);
    os[p][0] = sigm(o.x); os[p][1] = sigm(o.y); os[p][2] = sigm(o.z); os[p][3] = sigm(o.w);
  }
  for (int p = 0; p < 3; ++p) {
    const float* cp = cls + ((size_t)b * 240 + p * 80) * HW + loc;
    for (int c = 0; c < 80; ++c) {
      float4 v = *(const float4*)(cp + (size_t)c * HW);
      float sv[4] = { sigm(v.x) * os[p][0], sigm(v.y) * os[p][1],
                      sigm(v.z) * os[p][2], sigm(v.w) * os[p][3] };
#pragma unroll
      for (int k = 0; k < 4; ++k) {
        float sk = sv[k];
        if (sk > 0.25f) {
          uint32_t key = (__float_as_uint(sk) - 0x3E800000u) >> 10;
          if (key >= cut) {
            uint32_t pos = atomicAdd(&candCount[b], 1u);
            if (pos < CAP) {
              uint32_t flat = (uint32_t)((((c0 + k) * 3 + p) * 80) + c);
              cand[(size_t)b * CAP + pos] =
                  ((uint64_t)__float_as_uint(sk) << 32) | (uint64_t)(0xFFFFFFFFu - flat);
            }
          }
        }
      }
    }
  }
}

__global__ __launch_bounds__(1024) void k_sort_decode_fb(
    const uint64_t* __restrict__ cand, const uint32_t* __restrict__ candCount,
    const float* __restrict__ bbox0, const float* __restrict__ bbox1, const float* __restrict__ bbox2,
    const float* __restrict__ priors, const float* __restrict__ strides,
    float* __restrict__ topS, int* __restrict__ topLab, float* __restrict__ topBox,
    uint32_t* __restrict__ nvArr, const uint32_t* __restrict__ flags) {
  const int b = blockIdx.x;
  if (flags[b] == 0u) return;
  __shared__ uint64_t s[CAP];
  uint32_t cnt = candCount[b]; if (cnt > (uint32_t)CAP) cnt = CAP;
  for (int i = threadIdx.x; i < CAP; i += 1024)
    s[i] = (i < (int)cnt) ? cand[(size_t)b * CAP + i] : 0ull;
  __syncthreads();
  for (int k = 2; k <= CAP; k <<= 1) {
    for (int j = k >> 1; j > 0; j >>= 1) {
      for (int i = threadIdx.x; i < CAP; i += 1024) {
        int p = i ^ j;
        if (p > i) {
          uint64_t a = s[i], c = s[p];
          bool asc = (i & k) != 0;
          if (asc ? (a > c) : (a < c)) { s[i] = c; s[p] = a; }
        }
      }
      __syncthreads();
    }
  }
  const int NV = (int)(cnt < (uint32_t)PRE ? cnt : (uint32_t)PRE);
  if (threadIdx.x == 0) nvArr[b] = (uint32_t)NV;
  for (int t = threadIdx.x; t < PRE; t += 1024) {
    float sc = 0.0f; int lab = 0; float b0 = 0, b1 = 0, b2v = 0, b3 = 0;
    if (t < NV) {
      uint64_t key = s[t];
      sc = __uint_as_float((uint32_t)(key >> 32));
      uint32_t flat = 0xFFFFFFFFu - (uint32_t)(key & 0xFFFFFFFFull);
      uint32_t n = flat / 80u; lab = (int)(flat - n * 80u);
      uint32_t g = n / 3u; uint32_t p = n - g * 3u;
      int li, loc, HW; lvlinfo((int)g, li, loc, HW);
      const float* bb = li == 0 ? bbox0 : (li == 1 ? bbox1 : bbox2);
      size_t o = ((size_t)b * 12 + p * 4) * HW + loc;
      float p0 = sigm(bb[o]);
      float p1 = sigm(bb[o + (size_t)HW]);
      float p2 = sigm(bb[o + 2 * (size_t)HW]);
      float p3 = sigm(bb[o + 3 * (size_t)HW]);
      float4 pr = *(const float4*)(priors + (size_t)n * 4);
      float st = strides[n];
      float cx = (pr.x + pr.z) * 0.5f, cy = (pr.y + pr.w) * 0.5f;
      float w = pr.z - pr.x, hh = pr.w - pr.y;
      float xc = (p0 - 0.5f) * 2.0f * st + cx;
      float yc = (p1 - 0.5f) * 2.0f * st + cy;
      float wp = p2 * 2.0f; wp = wp * wp * w;
      float hp = p3 * 2.0f; hp = hp * hp * hh;
      b0 = xc - wp * 0.5f; b1 = yc - hp * 0.5f; b2v = xc + wp * 0.5f; b3 = yc + hp * 0.5f;
    }
    topS[(size_t)b * PRE + t] = sc;
    topLab[(size_t)b * PRE + t] = lab;
    *(float4*)(topBox + ((size_t)b * PRE + t) * 4) = make_float4(b0, b1, b2v, b3);
  }
}

// ---------------- K5+K6 fused: IoU bitmask in LDS + greedy scan + output ----------------
__global__ __launch_bounds__(256) void k_iou_scan(
    const float* __restrict__ topBox, const int* __restrict__ topLab,
    const float* __restrict__ topS, const uint32_t* __restrict__ nvArr,
    float* __restrict__ out) {
  __shared__ float4 bx[PRE];            // 16 KB
  __shared__ int lb[PRE];               // 4 KB
  __shared__ uint64_t rows[PRE * 16];   // 125 KB
  __shared__ uint64_t keepw[16];
  __shared__ uint32_t pref[17];
  const int b = blockIdx.x;
  const int NV = (int)nvArr[b];
  for (int i = threadIdx.x; i < PRE; i += 256) {
    bx[i] = *(const float4*)(topBox + ((size_t)b * PRE + i) * 4);
    lb[i] = topLab[(size_t)b * PRE + i];
  }
  __syncthreads();
  // IoU bitmask rows (j > i, same label, iou > thr)
  for (int task = threadIdx.x; task < PRE * 16; task += 256) {
    const int i = task >> 4, w = task & 15;
    uint64_t m = 0;
    if (i < NV) {
      const float4 a = bx[i]; const int la = lb[i];
      const float areaA = (a.z - a.x) * (a.w - a.y);
      const int j0 = w << 6;
      const int jend = (j0 + 64 < NV) ? j0 + 64 : NV;
      for (int j = (j0 > i + 1 ? j0 : i + 1); j < jend; ++j) {
        if (lb[j] != la) continue;
        const float4 c = bx[j];
        float xx1 = fmaxf(a.x, c.x), yy1 = fmaxf(a.y, c.y);
        float xx2 = fminf(a.z, c.z), yy2 = fminf(a.w, c.w);
        float iw = fmaxf(xx2 - xx1, 0.0f), ih = fmaxf(yy2 - yy1, 0.0f);
        float inter = iw * ih;
        float areaB = (c.z - c.x) * (c.w - c.y);
        float iou = inter / (areaA + areaB - inter + 1e-7f);
        if (iou > 0.65f) m |= (1ull << (j - j0));
      }
    }
    rows[i * 16 + w] = m;
  }
  __syncthreads();
  if (threadIdx.x < 64) {
    const int lane = threadIdx.x;
    uint64_t remv = 0, kw = 0;
    for (int w0 = 0; w0 * 64 < NV; ++w0) {
      uint64_t cur = (uint64_t)__shfl((unsigned long long)remv, w0);
      const int ie = (w0 * 64 + 64 < NV) ? w0 * 64 + 64 : NV;
      for (int i = w0 * 64; i < ie; ++i) {
        const int bi = i & 63;
        if (!((cur >> bi) & 1ull)) {
          uint64_t rl = rows[i * 16 + (lane & 15)];
          cur |= rows[i * 16 + w0];
          if (lane < 16) remv |= rl;
          if (lane == w0) kw |= (1ull << bi);
        }
      }
    }
    if (lane < 16) keepw[lane] = kw;
  }
  __syncthreads();
  if (threadIdx.x == 0) {
    uint32_t a = 0;
    for (int w = 0; w < 16; ++w) { pref[w] = a; a += (uint32_t)__popcll((unsigned long long)keepw[w]); }
    pref[16] = a;
  }
  __syncthreads();
  const uint32_t total = pref[16];
  const uint32_t num = total < (uint32_t)KEEP ? total : (uint32_t)KEEP;
  float* o_num = out;
  float* o_box = out + NIMG;
  float* o_s   = out + NIMG + NIMG * KEEP * 4;
  float* o_l   = o_s + NIMG * KEEP;
  if (threadIdx.x == 0) o_num[b] = (float)num;
  const int zstart = NV < KEEP ? NV : KEEP;
  for (int sidx = zstart + threadIdx.x; sidx < KEEP; sidx += 256) {
    ((float4*)o_box)[b * KEEP + sidx] = make_float4(0, 0, 0, 0);
    o_s[b * KEEP + sidx] = 0.0f;
    o_l[b * KEEP + sidx] = 0.0f;
  }
  for (int j = threadIdx.x; j < NV; j += 256) {
    const int wi = j >> 6, bi = j & 63;
    const uint64_t kword = keepw[wi];
    const int isk = (int)((kword >> bi) & 1ull);
    const uint32_t below = pref[wi] + (uint32_t)__popcll((unsigned long long)(kword & ((1ull << bi) - 1ull)));
    const uint32_t slot = isk ? below : (total + (uint32_t)j - below);
    if (slot < (uint32_t)KEEP) {
      ((float4*)o_box)[b * KEEP + slot] = bx[j];
      o_s[b * KEEP + slot] = isk ? topS[(size_t)b * PRE + j] : 0.0f;
      o_l[b * KEEP + slot] = (float)lb[j];
    }
  }
}

extern "C" void kernel_launch(void* const* d_in, const int* in_sizes, int n_in,
                              void* d_out, int out_size, void* d_ws, size_t ws_size,
                              hipStream_t stream) {
  (void)in_sizes; (void)n_in; (void)out_size; (void)ws_size;
  const float* cls0 = (const float*)d_in[0];
  const float* cls1 = (const float*)d_in[1];
  const float* cls2 = (const float*)d_in[2];
  const float* bbox0 = (const float*)d_in[3];
  const float* bbox1 = (const float*)d_in[4];
  const float* bbox2 = (const float*)d_in[5];
  const float* obj0 = (const float*)d_in[6];
  const float* obj1 = (const float*)d_in[7];
  const float* obj2 = (const float*)d_in[8];
  const float* priors = (const float*)d_in[9];
  const float* strides = (const float*)d_in[10];
  float* out = (float*)d_out;

  char* ws = (char*)d_ws;
  size_t off = 0;
  auto alloc = [&](size_t bytes) -> void* {
    void* p = ws + off;
    off = (off + bytes + 255) & ~(size_t)255;
    return p;
  };
  // small scratch packed for a single memset
  uint32_t* small     = (uint32_t*)alloc(4096);
  uint32_t* flags     = small;                 // [32]
  uint32_t* cnt75     = small + 32;            // [256]
  uint32_t* candCount = small + 288;           // [32]
  uint32_t* cutoff    = small + 320;           // [32]
  uint32_t* nvArr     = small + 352;           // [32]
  uint64_t* cand75    = (uint64_t*)alloc((size_t)NIMG * SUBS * SUBCAP * 8); // 4 MB
  uint32_t* hist      = (uint32_t*)alloc((size_t)NIMG * NBINS * 4);         // 2 MB (fb)
  uint64_t* cand      = (uint64_t*)alloc((size_t)NIMG * CAP * 8);           // 1 MB (fb)
  float*    topS      = (float*)alloc((size_t)NIMG * PRE * 4);
  int*      topLab    = (int*)alloc((size_t)NIMG * PRE * 4);
  float*    topBox    = (float*)alloc((size_t)NIMG * PRE * 16);

  hipMemsetAsync(small, 0, 4096, stream);

  k_pass1<<<dim3(18, NIMG), 256, 0, stream>>>(cls0, cls1, cls2, obj0, obj1, obj2,
                                              cnt75, cand75);
  k_gather<<<NIMG, 1024, 0, stream>>>(cand75, cnt75, flags, bbox0, bbox1, bbox2,
                                      priors, strides, topS, topLab, topBox, nvArr);
  k_zero_hist<<<256, 256, 0, stream>>>(hist, flags);
  dim3 gScan(9, NIMG);
  k_hist_fb<<<gScan, 256, 0, stream>>>(cls0, cls1, cls2, obj0, obj1, obj2, hist, flags);
  k_cutoff_fb<<<NIMG, 256, 0, stream>>>(hist, cutoff, flags);
  k_collect_fb<<<gScan, 256, 0, stream>>>(cls0, cls1, cls2, obj0, obj1, obj2,
                                          cutoff, candCount, cand, flags);
  k_sort_decode_fb<<<NIMG, 1024, 0, stream>>>(cand, candCount, bbox0, bbox1, bbox2,
                                              priors, strides, topS, topLab, topBox, nvArr, flags);
  k_iou_scan<<<NIMG, 256, 0, stream>>>(topBox, topLab, topS, nvArr, out);
}

// Round 7
// 371.012 us; speedup vs baseline: 2.2374x; 2.2374x over previous
//
#include <hip/hip_runtime.h>
#include <stdint.h>

#define NCLS 80
#define CELLS 8400      // 6400 + 1600 + 400
#define PRE 1000
#define KEEP 100
#define CAP 4096        // fallback candidate cap
#define NBINS 16384     // fallback histogram bins
#define NIMG 32
#define SUBS 8
#define SUBCAP 2048     // per-sub store cap (total 16384/image)
#define GBINS 4096      // gather-phase LDS histogram bins
#define COMPCAP 2048
#define T0 0.75f        // static pre-store threshold (top-1000 cutoff ~0.82 for N(0,1))
#define SCREEN 1.0886f  // logit(0.75)=1.0986 minus slack; exact test done on sigm product

__device__ __forceinline__ float sigm(float x) { return 1.0f / (1.0f + __expf(-x)); }

__device__ __forceinline__ void lvlinfo(int cell, int& li, int& loc, int& HW) {
  if (cell < 6400)      { li = 0; loc = cell;        HW = 6400; }
  else if (cell < 8000) { li = 1; loc = cell - 6400; HW = 1600; }
  else                  { li = 2; loc = cell - 8000; HW = 400;  }
}

// ---------------- K1: single full pass over cls/obj (R6 structure, now measurable) --------
__global__ __launch_bounds__(256) void k_pass1(
    const float* __restrict__ cls0, const float* __restrict__ cls1, const float* __restrict__ cls2,
    const float* __restrict__ obj0, const float* __restrict__ obj1, const float* __restrict__ obj2,
    uint32_t* __restrict__ cnt75, uint64_t* __restrict__ cand75) {
  const int b = blockIdx.y;
  const int bx = blockIdx.x;
  const int sb = bx >> 1;               // 9 spatial blocks
  const int h  = bx & 1;                // class chunk: [h*40, h*40+40)
  const int c0cell = (sb * 256 + threadIdx.x) * 4;
  if (c0cell >= CELLS) return;
  int li, loc, HW; lvlinfo(c0cell, li, loc, HW);
  const float* cls = li == 0 ? cls0 : (li == 1 ? cls1 : cls2);
  const float* obj = li == 0 ? obj0 : (li == 1 ? obj1 : obj2);

  float4 o0 = *(const float4*)(obj + ((size_t)b * 3 + 0) * HW + loc);
  float4 o1 = *(const float4*)(obj + ((size_t)b * 3 + 1) * HW + loc);
  float4 o2 = *(const float4*)(obj + ((size_t)b * 3 + 2) * HW + loc);
  float os[3][4];
  os[0][0] = sigm(o0.x); os[0][1] = sigm(o0.y); os[0][2] = sigm(o0.z); os[0][3] = sigm(o0.w);
  os[1][0] = sigm(o1.x); os[1][1] = sigm(o1.y); os[1][2] = sigm(o1.z); os[1][3] = sigm(o1.w);
  os[2][0] = sigm(o2.x); os[2][1] = sigm(o2.y); os[2][2] = sigm(o2.z); os[2][3] = sigm(o2.w);

  const int sub = bx & (SUBS - 1);

#define LD(dst, GQ) { _Pragma("unroll") for (int u = 0; u < 8; ++u) \
    dst[u] = *(const float4*)(cp + (size_t)((GQ) * 8 + u) * HW); }
#define PR(src, GQ) { \
    float mx = fmaxf(fmaxf(src[0].x, src[0].y), fmaxf(src[0].z, src[0].w)); \
    _Pragma("unroll") for (int u = 1; u < 8; ++u) \
      mx = fmaxf(mx, fmaxf(fmaxf(src[u].x, src[u].y), fmaxf(src[u].z, src[u].w))); \
    if (mx > SCREEN) { \
      _Pragma("unroll") for (int u = 0; u < 8; ++u) { \
        const int c = h * 40 + (GQ) * 8 + u; \
        float vv[4] = { src[u].x, src[u].y, src[u].z, src[u].w }; \
        _Pragma("unroll") for (int k = 0; k < 4; ++k) { \
          if (vv[k] > SCREEN) { \
            float s = sigm(vv[k]) * os[p][k]; \
            if (s > T0) { \
              uint32_t slot = atomicAdd(&cnt75[b * SUBS + sub], 1u); \
              if (slot < SUBCAP) { \
                uint32_t flat = (uint32_t)(((c0cell + k) * 3 + p) * 80 + c); \
                cand75[((size_t)(b * SUBS + sub)) * SUBCAP + slot] = \
                    ((uint64_t)__float_as_uint(s) << 32) | (uint64_t)(0xFFFFFFFFu - flat); \
              } } } } } } }

#pragma unroll
  for (int p = 0; p < 3; ++p) {
    const float* cp = cls + ((size_t)b * 240 + p * 80 + h * 40) * HW + loc;
    float4 va[8], vb[8];
    LD(va, 0)
    LD(vb, 1) PR(va, 0)
    LD(va, 2) PR(vb, 1)
    LD(vb, 3) PR(va, 2)
    LD(va, 4) PR(vb, 3)
    PR(va, 4)
  }
#undef LD
#undef PR
}

// ---------------- K3: per-image gather + exact top-1000 + decode; sets per-image fb flag ----
__global__ __launch_bounds__(1024) void k_gather(
    const uint64_t* __restrict__ cand75, const uint32_t* __restrict__ cnt75,
    uint32_t* __restrict__ flags,
    const float* __restrict__ bbox0, const float* __restrict__ bbox1, const float* __restrict__ bbox2,
    const float* __restrict__ priors, const float* __restrict__ strides,
    float* __restrict__ topS, int* __restrict__ topLab, float* __restrict__ topBox,
    uint32_t* __restrict__ nvArr) {
  __shared__ uint32_t hist[GBINS];
  __shared__ uint64_t comp[COMPCAP];
  __shared__ uint32_t seg[64];
  __shared__ uint32_t ncomp_s, cb_s;
  const int b = blockIdx.x;
  const int tid = threadIdx.x;
  uint32_t tot = 0; bool bad = false;
  for (int s = 0; s < SUBS; ++s) {
    uint32_t cc = cnt75[b * SUBS + s];
    tot += cc;
    if (cc > SUBCAP) bad = true;
  }
  if (tot < (uint32_t)PRE) bad = true;
  if (bad) { if (tid == 0) flags[b] = 1u; return; }

  for (int i = tid; i < GBINS; i += 1024) hist[i] = 0;
  if (tid == 0) ncomp_s = 0;
  __syncthreads();
  for (int s = 0; s < SUBS; ++s) {
    uint32_t c = cnt75[b * SUBS + s];
    const uint64_t* src = cand75 + ((size_t)(b * SUBS + s)) * SUBCAP;
    for (int i = tid; i < (int)c; i += 1024) {
      uint32_t hi = (uint32_t)(src[i] >> 32);
      uint32_t bin = (hi - 0x3F400000u) >> 10;
      if (bin > GBINS - 1) bin = GBINS - 1;
      atomicAdd(&hist[bin], 1u);
    }
  }
  __syncthreads();
  if (tid < 64) {
    uint32_t s = 0;
    for (int k = 0; k < 64; ++k) s += hist[tid * 64 + k];
    seg[tid] = s;
  }
  __syncthreads();
  if (tid == 0) {
    uint32_t acc = 0; int segi = 0;
    for (int i = 63; i >= 0; --i) {
      if (acc + seg[i] >= (uint32_t)PRE) { segi = i; break; }
      acc += seg[i];
    }
    uint32_t cb = 0;
    for (int k = 63; k >= 0; --k) {
      acc += hist[segi * 64 + k];
      if (acc >= (uint32_t)PRE) { cb = (uint32_t)(segi * 64 + k); break; }
    }
    cb_s = cb;
  }
  __syncthreads();
  const uint32_t cb = cb_s;
  for (int s = 0; s < SUBS; ++s) {
    uint32_t c = cnt75[b * SUBS + s];
    const uint64_t* src = cand75 + ((size_t)(b * SUBS + s)) * SUBCAP;
    for (int i = tid; i < (int)c; i += 1024) {
      uint64_t key = src[i];
      uint32_t hi = (uint32_t)(key >> 32);
      uint32_t bin = (hi - 0x3F400000u) >> 10;
      if (bin > GBINS - 1) bin = GBINS - 1;
      if (bin >= cb) {
        uint32_t pos = atomicAdd(&ncomp_s, 1u);
        if (pos < COMPCAP) comp[pos] = key;
      }
    }
  }
  __syncthreads();
  const uint32_t ncomp = ncomp_s;
  if (ncomp > COMPCAP) { if (tid == 0) flags[b] = 1u; return; }
  const int N = (ncomp <= 1024u) ? 1024 : COMPCAP;   // adaptive sort size
  for (int i = tid; i < N; i += 1024) if (i >= (int)ncomp) comp[i] = 0ull;
  __syncthreads();
  for (int k = 2; k <= N; k <<= 1) {
    for (int j = k >> 1; j > 0; j >>= 1) {
      for (int i = tid; i < N; i += 1024) {
        int p = i ^ j;
        if (p > i) {
          uint64_t a = comp[i], c = comp[p];
          bool asc = (i & k) != 0;
          if (asc ? (a > c) : (a < c)) { comp[i] = c; comp[p] = a; }
        }
      }
      __syncthreads();
    }
  }
  if (tid == 0) nvArr[b] = (uint32_t)PRE;
  for (int t = tid; t < PRE; t += 1024) {
    uint64_t key = comp[t];
    float sc = __uint_as_float((uint32_t)(key >> 32));
    uint32_t flat = 0xFFFFFFFFu - (uint32_t)(key & 0xFFFFFFFFull);
    uint32_t n = flat / 80u; int lab = (int)(flat - n * 80u);
    uint32_t g = n / 3u; uint32_t p = n - g * 3u;
    int li, loc, HW; lvlinfo((int)g, li, loc, HW);
    const float* bb = li == 0 ? bbox0 : (li == 1 ? bbox1 : bbox2);
    size_t o = ((size_t)b * 12 + p * 4) * HW + loc;
    float p0 = sigm(bb[o]);
    float p1 = sigm(bb[o + (size_t)HW]);
    float p2 = sigm(bb[o + 2 * (size_t)HW]);
    float p3 = sigm(bb[o + 3 * (size_t)HW]);
    float4 pr = *(const float4*)(priors + (size_t)n * 4);
    float st = strides[n];
    float cx = (pr.x + pr.z) * 0.5f, cy = (pr.y + pr.w) * 0.5f;
    float w = pr.z - pr.x, hh = pr.w - pr.y;
    float xc = (p0 - 0.5f) * 2.0f * st + cx;
    float yc = (p1 - 0.5f) * 2.0f * st + cy;
    float wp = p2 * 2.0f; wp = wp * wp * w;
    float hp = p3 * 2.0f; hp = hp * hp * hh;
    topS[(size_t)b * PRE + t] = sc;
    topLab[(size_t)b * PRE + t] = lab;
    *(float4*)(topBox + ((size_t)b * PRE + t) * 4) =
        make_float4(xc - wp * 0.5f, yc - hp * 0.5f, xc + wp * 0.5f, yc + hp * 0.5f);
  }
}

// ---------------- gated zero of fallback histogram (runs only if any flag set) ----------
__global__ __launch_bounds__(256) void k_zero_hist(uint32_t* __restrict__ hist,
                                                   const uint32_t* __restrict__ flags) {
  __shared__ uint32_t any;
  if (threadIdx.x == 0) {
    uint32_t a = 0;
    for (int i = 0; i < NIMG; ++i) a |= flags[i];
    any = a;
  }
  __syncthreads();
  if (!any) return;
  const int total = NIMG * NBINS;
  for (int i = blockIdx.x * 256 + threadIdx.x; i < total; i += gridDim.x * 256)
    hist[i] = 0;
}

// ================= FALLBACK PATH (per-image flag; never runs for typical data) ============
__global__ __launch_bounds__(256) void k_hist_fb(
    const float* __restrict__ cls0, const float* __restrict__ cls1, const float* __restrict__ cls2,
    const float* __restrict__ obj0, const float* __restrict__ obj1, const float* __restrict__ obj2,
    uint32_t* __restrict__ hist, const uint32_t* __restrict__ flags) {
  const int b = blockIdx.y;
  if (flags[b] == 0u) return;
  __shared__ uint32_t h[NBINS];
  for (int i = threadIdx.x; i < NBINS; i += 256) h[i] = 0;
  __syncthreads();
  const int c0 = (blockIdx.x * 256 + threadIdx.x) * 4;
  if (c0 < CELLS) {
    int li, loc, HW; lvlinfo(c0, li, loc, HW);
    const float* cls = li == 0 ? cls0 : (li == 1 ? cls1 : cls2);
    const float* obj = li == 0 ? obj0 : (li == 1 ? obj1 : obj2);
    float os[3][4];
#pragma unroll
    for (int p = 0; p < 3; ++p) {
      float4 o = *(const float4*)(obj + ((size_t)b * 3 + p) * HW + loc);
      os[p][0] = sigm(o.x); os[p][1] = sigm(o.y); os[p][2] = sigm(o.z); os[p][3] = sigm(o.w);
    }
    for (int p = 0; p < 3; ++p) {
      const float* cp = cls + ((size_t)b * 240 + p * 80) * HW + loc;
      for (int c = 0; c < 80; ++c) {
        float4 v = *(const float4*)(cp + (size_t)c * HW);
        float sv[4] = { sigm(v.x) * os[p][0], sigm(v.y) * os[p][1],
                        sigm(v.z) * os[p][2], sigm(v.w) * os[p][3] };
#pragma unroll
        for (int k = 0; k < 4; ++k) {
          if (sv[k] > 0.25f) {
            uint32_t key = (__float_as_uint(sv[k]) - 0x3E800000u) >> 10;
            if (key > NBINS - 1) key = NBINS - 1;
            atomicAdd(&h[key], 1u);
          }
        }
      }
    }
  }
  __syncthreads();
  for (int i = threadIdx.x; i < NBINS; i += 256) {
    uint32_t v = h[i];
    if (v) atomicAdd(&hist[(size_t)b * NBINS + i], v);
  }
}

__global__ __launch_bounds__(256) void k_cutoff_fb(const uint32_t* __restrict__ hist,
                                                   uint32_t* __restrict__ cutoff,
                                                   const uint32_t* __restrict__ flags) {
  const int b = blockIdx.x;
  if (flags[b] == 0u) return;
  __shared__ uint32_t seg[256];
  const uint32_t* hb = hist + (size_t)b * NBINS;
  uint32_t s = 0;
  for (int k = 0; k < 64; ++k) s += hb[threadIdx.x * 64 + k];
  seg[threadIdx.x] = s;
  __syncthreads();
  if (threadIdx.x == 0) {
    uint32_t acc = 0; int segi = -1;
    for (int i = 255; i >= 0; --i) {
      if (acc + seg[i] >= (uint32_t)PRE) { segi = i; break; }
      acc += seg[i];
    }
    uint32_t cut = 0;
    if (segi >= 0) {
      for (int k = 63; k >= 0; --k) {
        acc += hb[segi * 64 + k];
        if (acc >= (uint32_t)PRE) { cut = (uint32_t)(segi * 64 + k); break; }
      }
    }
    cutoff[b] = cut;
  }
}

__global__ __launch_bounds__(256) void k_collect_fb(
    const float* __restrict__ cls0, const float* __restrict__ cls1, const float* __restrict__ cls2,
    const float* __restrict__ obj0, const float* __restrict__ obj1, const float* __restrict__ obj2,
    const uint32_t* __restrict__ cutoff, uint32_t* __restrict__ candCount,
    uint64_t* __restrict__ cand, const uint32_t* __restrict__ flags) {
  const int b = blockIdx.y;
  if (flags[b] == 0u) return;
  const int c0 = (blockIdx.x * 256 + threadIdx.x) * 4;
  if (c0 >= CELLS) return;
  const uint32_t cut = cutoff[b];
  int li, loc, HW; lvlinfo(c0, li, loc, HW);
  const float* cls = li == 0 ? cls0 : (li == 1 ? cls1 : cls2);
  const float* obj = li == 0 ? obj0 : (li == 1 ? obj1 : obj2);
  float os[3][4];
#pragma unroll
  for (int p = 0; p < 3; ++p) {
    float4 o = *(const float4*)(obj + ((size_t)b * 3 + p) * HW + loc);
    os[p][0] = sigm(o.x); os[p][1] = sigm(o.y); os[p][2] = sigm(o.z); os[p][3] = sigm(o.w);
  }
  for (int p = 0; p < 3; ++p) {
    const float* cp = cls + ((size_t)b * 240 + p * 80) * HW + loc;
    for (int c = 0; c < 80; ++c) {
      float4 v = *(const float4*)(cp + (size_t)c * HW);
      float sv[4] = { sigm(v.x) * os[p][0], sigm(v.y) * os[p][1],
                      sigm(v.z) * os[p][2], sigm(v.w) * os[p][3] };
#pragma unroll
      for (int k = 0; k < 4; ++k) {
        float sk = sv[k];
        if (sk > 0.25f) {
          uint32_t key = (__float_as_uint(sk) - 0x3E800000u) >> 10;
          if (key >= cut) {
            uint32_t pos = atomicAdd(&candCount[b], 1u);
            if (pos < CAP) {
              uint32_t flat = (uint32_t)((((c0 + k) * 3 + p) * 80) + c);
              cand[(size_t)b * CAP + pos] =
                  ((uint64_t)__float_as_uint(sk) << 32) | (uint64_t)(0xFFFFFFFFu - flat);
            }
          }
        }
      }
    }
  }
}

__global__ __launch_bounds__(1024) void k_sort_decode_fb(
    const uint64_t* __restrict__ cand, const uint32_t* __restrict__ candCount,
    const float* __restrict__ bbox0, const float* __restrict__ bbox1, const float* __restrict__ bbox2,
    const float* __restrict__ priors, const float* __restrict__ strides,
    float* __restrict__ topS, int* __restrict__ topLab, float* __restrict__ topBox,
    uint32_t* __restrict__ nvArr, const uint32_t* __restrict__ flags) {
  const int b = blockIdx.x;
  if (flags[b] == 0u) return;
  __shared__ uint64_t s[CAP];
  uint32_t cnt = candCount[b]; if (cnt > (uint32_t)CAP) cnt = CAP;
  for (int i = threadIdx.x; i < CAP; i += 1024)
    s[i] = (i < (int)cnt) ? cand[(size_t)b * CAP + i] : 0ull;
  __syncthreads();
  for (int k = 2; k <= CAP; k <<= 1) {
    for (int j = k >> 1; j > 0; j >>= 1) {
      for (int i = threadIdx.x; i < CAP; i += 1024) {
        int p = i ^ j;
        if (p > i) {
          uint64_t a = s[i], c = s[p];
          bool asc = (i & k) != 0;
          if (asc ? (a > c) : (a < c)) { s[i] = c; s[p] = a; }
        }
      }
      __syncthreads();
    }
  }
  const int NV = (int)(cnt < (uint32_t)PRE ? cnt : (uint32_t)PRE);
  if (threadIdx.x == 0) nvArr[b] = (uint32_t)NV;
  for (int t = threadIdx.x; t < PRE; t += 1024) {
    float sc = 0.0f; int lab = 0; float b0 = 0, b1 = 0, b2v = 0, b3 = 0;
    if (t < NV) {
      uint64_t key = s[t];
      sc = __uint_as_float((uint32_t)(key >> 32));
      uint32_t flat = 0xFFFFFFFFu - (uint32_t)(key & 0xFFFFFFFFull);
      uint32_t n = flat / 80u; lab = (int)(flat - n * 80u);
      uint32_t g = n / 3u; uint32_t p = n - g * 3u;
      int li, loc, HW; lvlinfo((int)g, li, loc, HW);
      const float* bb = li == 0 ? bbox0 : (li == 1 ? bbox1 : bbox2);
      size_t o = ((size_t)b * 12 + p * 4) * HW + loc;
      float p0 = sigm(bb[o]);
      float p1 = sigm(bb[o + (size_t)HW]);
      float p2 = sigm(bb[o + 2 * (size_t)HW]);
      float p3 = sigm(bb[o + 3 * (size_t)HW]);
      float4 pr = *(const float4*)(priors + (size_t)n * 4);
      float st = strides[n];
      float cx = (pr.x + pr.z) * 0.5f, cy = (pr.y + pr.w) * 0.5f;
      float w = pr.z - pr.x, hh = pr.w - pr.y;
      float xc = (p0 - 0.5f) * 2.0f * st + cx;
      float yc = (p1 - 0.5f) * 2.0f * st + cy;
      float wp = p2 * 2.0f; wp = wp * wp * w;
      float hp = p3 * 2.0f; hp = hp * hp * hh;
      b0 = xc - wp * 0.5f; b1 = yc - hp * 0.5f; b2v = xc + wp * 0.5f; b3 = yc + hp * 0.5f;
    }
    topS[(size_t)b * PRE + t] = sc;
    topLab[(size_t)b * PRE + t] = lab;
    *(float4*)(topBox + ((size_t)b * PRE + t) * 4) = make_float4(b0, b1, b2v, b3);
  }
}

// ---------------- K5: IoU suppression bitmask (63 blocks/image) ----------------
__global__ __launch_bounds__(256) void k_iou(
    const float* __restrict__ topBox, const int* __restrict__ topLab,
    const uint32_t* __restrict__ nvArr, uint64_t* __restrict__ mask) {
  __shared__ float4 bx[PRE];
  __shared__ int lb[PRE];
  const int b = blockIdx.y;
  const int NV = (int)nvArr[b];
  for (int i = threadIdx.x; i < PRE; i += 256) {
    bx[i] = *(const float4*)(topBox + ((size_t)b * PRE + i) * 4);
    lb[i] = topLab[(size_t)b * PRE + i];
  }
  __syncthreads();
  for (int task = blockIdx.x * 256 + threadIdx.x; task < PRE * 16; task += gridDim.x * 256) {
    const int i = task >> 4, w = task & 15;
    uint64_t m = 0;
    if (i < NV) {
      const float4 a = bx[i]; const int la = lb[i];
      const float areaA = (a.z - a.x) * (a.w - a.y);
      const int j0 = w << 6;
      const int jend = (j0 + 64 < NV) ? j0 + 64 : NV;
      for (int j = (j0 > i + 1 ? j0 : i + 1); j < jend; ++j) {
        if (lb[j] != la) continue;
        const float4 c = bx[j];
        float xx1 = fmaxf(a.x, c.x), yy1 = fmaxf(a.y, c.y);
        float xx2 = fminf(a.z, c.z), yy2 = fminf(a.w, c.w);
        float iw = fmaxf(xx2 - xx1, 0.0f), ih = fmaxf(yy2 - yy1, 0.0f);
        float inter = iw * ih;
        float areaB = (c.z - c.x) * (c.w - c.y);
        float iou = inter / (areaA + areaB - inter + 1e-7f);
        if (iou > 0.65f) m |= (1ull << (j - j0));
      }
    }
    mask[((size_t)b * PRE + i) * 16 + w] = m;
  }
}

// ---------------- K6: serial greedy scan (branchless, pipelined) + output assembly --------
__global__ __launch_bounds__(256) void k_scan_out(
    const uint64_t* __restrict__ mask, const float* __restrict__ topS,
    const int* __restrict__ topLab, const float* __restrict__ topBox,
    const uint32_t* __restrict__ nvArr, float* __restrict__ out) {
  __shared__ uint64_t rows[PRE * 16];   // 125 KB
  __shared__ uint64_t keepw[16];
  __shared__ uint32_t pref[17];
  const int b = blockIdx.x;
  const int NV = (int)nvArr[b];
  for (int i = threadIdx.x; i < NV * 16; i += 256) rows[i] = mask[(size_t)b * PRE * 16 + i];
  __syncthreads();
  if (threadIdx.x < 64) {
    const int lane = threadIdx.x;
    uint64_t remv = 0, kw = 0;
    for (int w0 = 0; w0 * 64 < NV; ++w0) {
      uint64_t cur = (uint64_t)__shfl((unsigned long long)remv, w0);
      const int ie = (w0 * 64 + 64 < NV) ? w0 * 64 + 64 : NV;
      for (int i = w0 * 64; i < ie; ++i) {
        const int bi = i & 63;
        // unconditional loads: addresses depend only on i -> pipeline ahead of the
        // serial cur-chain (which is now pure VALU: test, mask, or).
        uint64_t rl = rows[i * 16 + (lane & 15)];
        uint64_t cw = rows[i * 16 + w0];
        const uint64_t keepm = ((cur >> bi) & 1ull) ? 0ull : ~0ull;
        cur |= cw & keepm;
        remv |= rl & keepm;                       // only lanes<16 consumed below
        kw |= (lane == w0) ? ((1ull << bi) & keepm) : 0ull;
      }
    }
    if (lane < 16) keepw[lane] = kw;
  }
  __syncthreads();
  if (threadIdx.x == 0) {
    uint32_t a = 0;
    for (int w = 0; w < 16; ++w) { pref[w] = a; a += (uint32_t)__popcll((unsigned long long)keepw[w]); }
    pref[16] = a;
  }
  __syncthreads();
  const uint32_t total = pref[16];
  const uint32_t num = total < (uint32_t)KEEP ? total : (uint32_t)KEEP;
  float* o_num = out;
  float* o_box = out + NIMG;
  float* o_s   = out + NIMG + NIMG * KEEP * 4;
  float* o_l   = o_s + NIMG * KEEP;
  if (threadIdx.x == 0) o_num[b] = (float)num;
  const int zstart = NV < KEEP ? NV : KEEP;
  for (int sidx = zstart + threadIdx.x; sidx < KEEP; sidx += 256) {
    ((float4*)o_box)[b * KEEP + sidx] = make_float4(0, 0, 0, 0);
    o_s[b * KEEP + sidx] = 0.0f;
    o_l[b * KEEP + sidx] = 0.0f;
  }
  for (int j = threadIdx.x; j < NV; j += 256) {
    const int wi = j >> 6, bi = j & 63;
    const uint64_t kword = keepw[wi];
    const int isk = (int)((kword >> bi) & 1ull);
    const uint32_t below = pref[wi] + (uint32_t)__popcll((unsigned long long)(kword & ((1ull << bi) - 1ull)));
    const uint32_t slot = isk ? below : (total + (uint32_t)j - below);
    if (slot < (uint32_t)KEEP) {
      ((float4*)o_box)[b * KEEP + slot] = *(const float4*)(topBox + ((size_t)b * PRE + j) * 4);
      o_s[b * KEEP + slot] = isk ? topS[(size_t)b * PRE + j] : 0.0f;
      o_l[b * KEEP + slot] = (float)topLab[(size_t)b * PRE + j];
    }
  }
}

extern "C" void kernel_launch(void* const* d_in, const int* in_sizes, int n_in,
                              void* d_out, int out_size, void* d_ws, size_t ws_size,
                              hipStream_t stream) {
  (void)in_sizes; (void)n_in; (void)out_size; (void)ws_size;
  const float* cls0 = (const float*)d_in[0];
  const float* cls1 = (const float*)d_in[1];
  const float* cls2 = (const float*)d_in[2];
  const float* bbox0 = (const float*)d_in[3];
  const float* bbox1 = (const float*)d_in[4];
  const float* bbox2 = (const float*)d_in[5];
  const float* obj0 = (const float*)d_in[6];
  const float* obj1 = (const float*)d_in[7];
  const float* obj2 = (const float*)d_in[8];
  const float* priors = (const float*)d_in[9];
  const float* strides = (const float*)d_in[10];
  float* out = (float*)d_out;

  char* ws = (char*)d_ws;
  size_t off = 0;
  auto alloc = [&](size_t bytes) -> void* {
    void* p = ws + off;
    off = (off + bytes + 255) & ~(size_t)255;
    return p;
  };
  // small scratch packed for a single memset
  uint32_t* small     = (uint32_t*)alloc(4096);
  uint32_t* flags     = small;                 // [32]
  uint32_t* cnt75     = small + 32;            // [256]
  uint32_t* candCount = small + 288;           // [32]
  uint32_t* cutoff    = small + 320;           // [32]
  uint32_t* nvArr     = small + 352;           // [32]
  uint64_t* cand75    = (uint64_t*)alloc((size_t)NIMG * SUBS * SUBCAP * 8); // 4 MB
  uint32_t* hist      = (uint32_t*)alloc((size_t)NIMG * NBINS * 4);         // 2 MB (fb)
  uint64_t* cand      = (uint64_t*)alloc((size_t)NIMG * CAP * 8);           // 1 MB (fb)
  float*    topS      = (float*)alloc((size_t)NIMG * PRE * 4);
  int*      topLab    = (int*)alloc((size_t)NIMG * PRE * 4);
  float*    topBox    = (float*)alloc((size_t)NIMG * PRE * 16);
  uint64_t* maskbuf   = (uint64_t*)alloc((size_t)NIMG * PRE * 16 * 8);      // 4 MB

  hipMemsetAsync(small, 0, 4096, stream);

  k_pass1<<<dim3(18, NIMG), 256, 0, stream>>>(cls0, cls1, cls2, obj0, obj1, obj2,
                                              cnt75, cand75);
  k_gather<<<NIMG, 1024, 0, stream>>>(cand75, cnt75, flags, bbox0, bbox1, bbox2,
                                      priors, strides, topS, topLab, topBox, nvArr);
  k_zero_hist<<<256, 256, 0, stream>>>(hist, flags);
  dim3 gScan(9, NIMG);
  k_hist_fb<<<gScan, 256, 0, stream>>>(cls0, cls1, cls2, obj0, obj1, obj2, hist, flags);
  k_cutoff_fb<<<NIMG, 256, 0, stream>>>(hist, cutoff, flags);
  k_collect_fb<<<gScan, 256, 0, stream>>>(cls0, cls1, cls2, obj0, obj1, obj2,
                                          cutoff, candCount, cand, flags);
  k_sort_decode_fb<<<NIMG, 1024, 0, stream>>>(cand, candCount, bbox0, bbox1, bbox2,
                                              priors, strides, topS, topLab, topBox, nvArr, flags);
  k_iou<<<dim3(63, NIMG), 256, 0, stream>>>(topBox, topLab, nvArr, maskbuf);
  k_scan_out<<<NIMG, 256, 0, stream>>>(maskbuf, topS, topLab, topBox, nvArr, out);
}